// Round 5
// baseline (1586.823 us; speedup 1.0000x reference)
//
#include <hip/hip_runtime.h>
#include <hip/hip_bf16.h>

#define N_TOK 4096
#define DIM   1024
#define VOCAB 32000
#define BM 128
#define BN 128
#define BKB 128         // K-bytes per stage = 128 fp8 elems = one 16x16x128 MFMA k-step
#define SMOOTH 0.1f
#define WSCALE 32.0f    // W quantized as W*32 (avoids e4m3 subnormal hole); B-scale = 2^-5

typedef __attribute__((ext_vector_type(8))) int   int8v;
typedef __attribute__((ext_vector_type(4))) int   int4v;
typedef __attribute__((ext_vector_type(4))) float float4v;

// E8M0 scales: all 4 bytes identical -> opsel-invariant, uniform across k-blocks
#define SCALE_ONE   0x7F7F7F7F   // 2^0
#define SCALE_W     0x7A7A7A7A   // 2^-5

// f32 -> fp8 e4m3 (OCP, saturating) for BOTH tensors in one dispatch.
// X stored as-is (sigma=1, normal range); W stored *32.
__global__ void cvt_fp8_2(const float* __restrict__ a, unsigned int* __restrict__ da, int n4a,
                          const float* __restrict__ b, unsigned int* __restrict__ db, int n4b) {
  int i = blockIdx.x * blockDim.x + threadIdx.x;
  const float4* s; unsigned int* d; int j; float sc;
  if (i < n4a)            { s = (const float4*)a; d = da; j = i;       sc = 1.0f;   }
  else if (i < n4a + n4b) { s = (const float4*)b; d = db; j = i - n4a; sc = WSCALE; }
  else return;
  float4 v = s[j];
  int p = 0;
  p = __builtin_amdgcn_cvt_pk_fp8_f32(v.x * sc, v.y * sc, p, false);  // bytes 0,1
  p = __builtin_amdgcn_cvt_pk_fp8_f32(v.z * sc, v.w * sc, p, true);   // bytes 2,3
  d[j] = (unsigned int)p;
}

__device__ __forceinline__ void gload_lds16(const unsigned char* g, unsigned char* l) {
  __builtin_amdgcn_global_load_lds((const __attribute__((address_space(1))) unsigned int*)g,
                                   (__attribute__((address_space(3))) unsigned int*)l,
                                   16, 0, 0);
}

// logit[n, y_n] in exact f32: one wave per token row (0.9-weighted term stays exact).
__global__ __launch_bounds__(256)
void tgt_dot(const float* __restrict__ x, const float* __restrict__ W,
             const int* __restrict__ y, float* __restrict__ tgtRow) {
  const int n = blockIdx.x * 4 + (threadIdx.x >> 6);
  const int lane = threadIdx.x & 63;
  const float4* xr = (const float4*)(x + (size_t)n * DIM);
  const float4* wr = (const float4*)(W + (size_t)y[n] * DIM);
  float d = 0.f;
#pragma unroll
  for (int i = 0; i < 4; ++i) {
    float4 a = xr[lane + 64 * i], b = wr[lane + 64 * i];
    d += a.x * b.x + a.y * b.y + a.z * b.z + a.w * b.w;
  }
#pragma unroll
  for (int off = 32; off > 0; off >>= 1) d += __shfl_xor(d, off, 64);
  if (lane == 0) tgtRow[n] = d;
}

// C = X * W^T in MX-fp8 (mfma_scale 16x16x128, A-scale 1, B-scale 2^-5) with
// fused per-row sum(exp) / sum. 128x128 tile, 4 waves 2x2, 8 K-iters.
// XOR-swizzled LDS (R4-verified 0-conflict): LDS slot cb holds global
// colblock cb ^ (row&7)  (cb = 16B block; row stride 128 B = 32 banks).
__global__ __launch_bounds__(256, 3)
void gemm_ce(const unsigned char* __restrict__ Xf8, const unsigned char* __restrict__ Wf8,
             float* __restrict__ rowExp, float* __restrict__ rowSum) {
  __shared__ __align__(16) unsigned char As[BM * BKB];  // 16 KB
  __shared__ __align__(16) unsigned char Bs[BN * BKB];  // 16 KB

  const int ib = blockIdx.x;   // token tile (32) fastest: XCD = ib%8 (W reuse per XCD)
  const int jb = blockIdx.y;   // vocab tile (250)
  const int row0 = ib * BM;
  const int col0 = jb * BN;

  const int tid  = threadIdx.x;
  const int wv   = tid >> 6;
  const int lane = tid & 63;
  const int wr = wv >> 1, wc = wv & 1;
  const int quad = lane >> 4;
  const int r16  = lane & 15;
  // staging: 1 KB per inst = 8 rows x 8 colblocks(16B); LDS slot fixed at
  // base+lane*16; lane FETCHES global colblock (lane&7)^(lrow&7).
  const int lrow = lane >> 3;
  const int gcb  = (lane & 7) ^ (lrow & 7);
  const int r8   = r16 & 7;

  float4v acc[4][4];
#pragma unroll
  for (int i = 0; i < 4; ++i)
#pragma unroll
    for (int j = 0; j < 4; ++j) acc[i][j] = (float4v){0.f, 0.f, 0.f, 0.f};

  for (int kk = 0; kk < DIM; kk += BKB) {
    __syncthreads();   // prior ds_reads done before overwrite
#pragma unroll
    for (int c = 0; c < 4; ++c) {
      const int rA = wv * 32 + c * 8;   // wave-uniform 8-row slab base
      gload_lds16(Xf8 + (size_t)(row0 + rA + lrow) * DIM + kk + gcb * 16, &As[rA * BKB]);
      gload_lds16(Wf8 + (size_t)(col0 + rA + lrow) * DIM + kk + gcb * 16, &Bs[rA * BKB]);
    }
    __syncthreads();   // staging visible (vmcnt drain)

    // A/B fragment: 32 fp8 per lane, k-run = quad*32 + [0,32). Any consistent
    // A/B k-packing is correct (uniform scales; dot is k-permutation-invariant).
    int8v bf[4];
#pragma unroll
    for (int j = 0; j < 4; ++j) {
      const int rowB = (wc * 64 + j * 16 + r16) * BKB;
      union { int8v v8; int4v v4[2]; } u;
      u.v4[0] = *(const int4v*)&Bs[rowB + (((quad * 2)     ^ r8) << 4)];
      u.v4[1] = *(const int4v*)&Bs[rowB + (((quad * 2 + 1) ^ r8) << 4)];
      bf[j] = u.v8;
    }
#pragma unroll
    for (int i = 0; i < 4; ++i) {
      const int rowA = (wr * 64 + i * 16 + r16) * BKB;
      union { int8v v8; int4v v4[2]; } u;
      u.v4[0] = *(const int4v*)&As[rowA + (((quad * 2)     ^ r8) << 4)];
      u.v4[1] = *(const int4v*)&As[rowA + (((quad * 2 + 1) ^ r8) << 4)];
      const int8v af = u.v8;
#pragma unroll
      for (int j = 0; j < 4; ++j)
        acc[i][j] = __builtin_amdgcn_mfma_scale_f32_16x16x128_f8f6f4(
            af, bf[j], acc[i][j],
            0, 0,                 // cbsz=fp8(e4m3), blgp=fp8(e4m3)
            0, SCALE_ONE,         // A scale 2^0
            0, SCALE_W);          // B scale 2^-5 (undoes W*32)
    }
  }

  // Fused epilogue: per-row sum(exp(logit)), sum(logit).
  // C/D layout (shape-determined): col = r16, row = quad*4 + reg
#pragma unroll
  for (int i = 0; i < 4; ++i)
#pragma unroll
    for (int r = 0; r < 4; ++r) {
      float se = 0.f, ss = 0.f;
#pragma unroll
      for (int j = 0; j < 4; ++j) {
        const float v = acc[i][j][r];
        ss += v;
        se += __expf(v);
      }
#pragma unroll
      for (int off = 1; off < 16; off <<= 1) {
        se += __shfl_xor(se, off, 64);
        ss += __shfl_xor(ss, off, 64);
      }
      if (r16 == 0) {
        const int rloc = wr * 64 + i * 16 + quad * 4 + r;
        atomicAdd(&rowExp[row0 + rloc], se);
        atomicAdd(&rowSum[row0 + rloc], ss);
      }
    }
}

// loss = (1/N) sum lse - (1-s)/N * sum tgt - s/(N*V) * sum(all logits)
__global__ void finalize_kernel(const float* __restrict__ rowExp, const float* __restrict__ rowSum,
                                const float* __restrict__ tgtRow, float* __restrict__ out) {
  __shared__ float s1[256], s2[256], s3[256];
  const int t = threadIdx.x;
  float a = 0.f, b = 0.f, c = 0.f;
  for (int n = t; n < N_TOK; n += 256) {
    a += logf(rowExp[n]);
    b += rowSum[n];
    c += tgtRow[n];
  }
  s1[t] = a; s2[t] = b; s3[t] = c;
  __syncthreads();
  for (int o = 128; o > 0; o >>= 1) {
    if (t < o) { s1[t] += s1[t + o]; s2[t] += s2[t + o]; s3[t] += s3[t + o]; }
    __syncthreads();
  }
  if (t == 0) {
    const float inviN = 1.0f / (float)N_TOK;
    out[0] = s1[0] * inviN
           - (1.0f - SMOOTH) * s3[0] * inviN
           - SMOOTH * s2[0] / ((float)N_TOK * (float)VOCAB);
  }
}

extern "C" void kernel_launch(void* const* d_in, const int* in_sizes, int n_in,
                              void* d_out, int out_size, void* d_ws, size_t ws_size,
                              hipStream_t stream) {
  const float* x = (const float*)d_in[0];
  const float* W = (const float*)d_in[1];
  const int*   y = (const int*)d_in[2];
  float* out = (float*)d_out;

  char* ws = (char*)d_ws;
  float* rowExp = (float*)(ws);              // 4096 f32
  float* rowSum = (float*)(ws + 16384);      // 4096 f32
  float* tgtRow = (float*)(ws + 32768);      // 4096 f32 (fully written, no memset)
  unsigned char* Xf8 = (unsigned char*)(ws + 65536);                        // 4.19 MB
  unsigned char* Wf8 = (unsigned char*)(ws + 65536 + (size_t)N_TOK * DIM);  // 32.77 MB

  hipMemsetAsync(ws, 0, 32768, stream);  // zero rowExp/rowSum (ws poisoned 0xAA)

  tgt_dot<<<N_TOK / 4, 256, 0, stream>>>(x, W, y, tgtRow);

  const int n4x = N_TOK * DIM / 4, n4w = VOCAB * DIM / 4;
  cvt_fp8_2<<<(n4x + n4w + 255) / 256, 256, 0, stream>>>(x, (unsigned int*)Xf8, n4x,
                                                         W, (unsigned int*)Wf8, n4w);

  dim3 grid(N_TOK / BM, VOCAB / BN);  // (32, 250)
  gemm_ce<<<grid, 256, 0, stream>>>(Xf8, Wf8, rowExp, rowSum);

  finalize_kernel<<<1, 256, 0, stream>>>(rowExp, rowSum, tgtRow, out);
}

// Round 6
// 1554.964 us; speedup vs baseline: 1.0205x; 1.0205x over previous
//
#include <hip/hip_runtime.h>
#include <hip/hip_bf16.h>

#define N_TOK 4096
#define DIM   1024
#define VOCAB 32000
#define BM 128
#define BN 128
#define BKB 128         // K-bytes per stage = 128 fp8 elems = one 16x16x128 MFMA k-step
#define SMOOTH 0.1f
#define WSCALE 32.0f    // W quantized as W*32 (avoids e4m3 subnormal hole); B-scale = 2^-5

typedef __attribute__((ext_vector_type(8))) int   int8v;
typedef __attribute__((ext_vector_type(4))) int   int4v;
typedef __attribute__((ext_vector_type(4))) float float4v;

// E8M0 scales: all 4 bytes identical -> opsel-invariant, uniform across k-blocks
#define SCALE_ONE   0x7F7F7F7F   // 2^0
#define SCALE_W     0x7A7A7A7A   // 2^-5

// f32 -> fp8 e4m3 (OCP, saturating) for BOTH tensors in one dispatch.
// X stored as-is (sigma=1, normal range); W stored *32.
__global__ void cvt_fp8_2(const float* __restrict__ a, unsigned int* __restrict__ da, int n4a,
                          const float* __restrict__ b, unsigned int* __restrict__ db, int n4b) {
  int i = blockIdx.x * blockDim.x + threadIdx.x;
  const float4* s; unsigned int* d; int j; float sc;
  if (i < n4a)            { s = (const float4*)a; d = da; j = i;       sc = 1.0f;   }
  else if (i < n4a + n4b) { s = (const float4*)b; d = db; j = i - n4a; sc = WSCALE; }
  else return;
  float4 v = s[j];
  int p = 0;
  p = __builtin_amdgcn_cvt_pk_fp8_f32(v.x * sc, v.y * sc, p, false);  // bytes 0,1
  p = __builtin_amdgcn_cvt_pk_fp8_f32(v.z * sc, v.w * sc, p, true);   // bytes 2,3
  d[j] = (unsigned int)p;
}

__device__ __forceinline__ void gload_lds16(const unsigned char* g, unsigned char* l) {
  __builtin_amdgcn_global_load_lds((const __attribute__((address_space(1))) unsigned int*)g,
                                   (__attribute__((address_space(3))) unsigned int*)l,
                                   16, 0, 0);
}

// logit[n, y_n] in exact f32: one wave per token row (0.9-weighted term stays exact).
__global__ __launch_bounds__(256)
void tgt_dot(const float* __restrict__ x, const float* __restrict__ W,
             const int* __restrict__ y, float* __restrict__ tgtRow) {
  const int n = blockIdx.x * 4 + (threadIdx.x >> 6);
  const int lane = threadIdx.x & 63;
  const float4* xr = (const float4*)(x + (size_t)n * DIM);
  const float4* wr = (const float4*)(W + (size_t)y[n] * DIM);
  float d = 0.f;
#pragma unroll
  for (int i = 0; i < 4; ++i) {
    float4 a = xr[lane + 64 * i], b = wr[lane + 64 * i];
    d += a.x * b.x + a.y * b.y + a.z * b.z + a.w * b.w;
  }
#pragma unroll
  for (int off = 32; off > 0; off >>= 1) d += __shfl_xor(d, off, 64);
  if (lane == 0) tgtRow[n] = d;
}

// C = X * W^T in MX-fp8 (mfma_scale 16x16x128, A-scale 1, B-scale 2^-5) with
// fused per-row sum(exp) / sum. 128x128 tile, 4 waves 2x2, 8 K-iters.
// XOR-swizzled LDS (R4-verified 0-conflict): LDS slot cb holds global
// colblock cb ^ (row&7); reader XORs with its own row&7 -> cancels, so the
// effective k-mapping is lane-independent (A/B consistent).
// Fragments assembled via __builtin_shufflevector (REGISTER op) -- the R5
// union punning forced the aggregates through scratch: 2.7 GB spill writes.
__global__ __launch_bounds__(256, 3)
void gemm_ce(const unsigned char* __restrict__ Xf8, const unsigned char* __restrict__ Wf8,
             float* __restrict__ rowExp, float* __restrict__ rowSum) {
  __shared__ __align__(16) unsigned char As[BM * BKB];  // 16 KB
  __shared__ __align__(16) unsigned char Bs[BN * BKB];  // 16 KB

  const int ib = blockIdx.x;   // token tile (32) fastest: XCD = ib%8 (W reuse per XCD)
  const int jb = blockIdx.y;   // vocab tile (250)
  const int row0 = ib * BM;
  const int col0 = jb * BN;

  const int tid  = threadIdx.x;
  const int wv   = tid >> 6;
  const int lane = tid & 63;
  const int wr = wv >> 1, wc = wv & 1;
  const int quad = lane >> 4;
  const int r16  = lane & 15;
  // staging: 1 KB per inst = 8 rows x 8 colblocks(16B); LDS slot fixed at
  // base+lane*16; lane FETCHES global colblock (lane&7)^(lrow&7).
  const int lrow = lane >> 3;
  const int gcb  = (lane & 7) ^ (lrow & 7);
  const int r8   = r16 & 7;

  float4v acc[4][4];
#pragma unroll
  for (int i = 0; i < 4; ++i)
#pragma unroll
    for (int j = 0; j < 4; ++j) acc[i][j] = (float4v){0.f, 0.f, 0.f, 0.f};

  const int cbLo = ((quad * 2)     ^ r8) << 4;   // LDS byte offset of k-half 0
  const int cbHi = ((quad * 2 + 1) ^ r8) << 4;   // k-half 1

  for (int kk = 0; kk < DIM; kk += BKB) {
    __syncthreads();   // prior ds_reads done before overwrite
#pragma unroll
    for (int c = 0; c < 4; ++c) {
      const int rA = wv * 32 + c * 8;   // wave-uniform 8-row slab base
      gload_lds16(Xf8 + (size_t)(row0 + rA + lrow) * DIM + kk + gcb * 16, &As[rA * BKB]);
      gload_lds16(Wf8 + (size_t)(col0 + rA + lrow) * DIM + kk + gcb * 16, &Bs[rA * BKB]);
    }
    __syncthreads();   // staging visible (vmcnt drain)

    int8v bf[4];
#pragma unroll
    for (int j = 0; j < 4; ++j) {
      const int rowB = (wc * 64 + j * 16 + r16) * BKB;
      const int4v lo = *(const int4v*)&Bs[rowB + cbLo];
      const int4v hi = *(const int4v*)&Bs[rowB + cbHi];
      bf[j] = __builtin_shufflevector(lo, hi, 0, 1, 2, 3, 4, 5, 6, 7);
    }
#pragma unroll
    for (int i = 0; i < 4; ++i) {
      const int rowA = (wr * 64 + i * 16 + r16) * BKB;
      const int4v lo = *(const int4v*)&As[rowA + cbLo];
      const int4v hi = *(const int4v*)&As[rowA + cbHi];
      const int8v af = __builtin_shufflevector(lo, hi, 0, 1, 2, 3, 4, 5, 6, 7);
#pragma unroll
      for (int j = 0; j < 4; ++j)
        acc[i][j] = __builtin_amdgcn_mfma_scale_f32_16x16x128_f8f6f4(
            af, bf[j], acc[i][j],
            0, 0,                 // cbsz=fp8(e4m3), blgp=fp8(e4m3)
            0, SCALE_ONE,         // A scale 2^0
            0, SCALE_W);          // B scale 2^-5 (undoes W*32)
    }
  }

  // Fused epilogue: per-row sum(exp(logit)), sum(logit).
  // C/D layout (shape-determined): col = r16, row = quad*4 + reg
#pragma unroll
  for (int i = 0; i < 4; ++i)
#pragma unroll
    for (int r = 0; r < 4; ++r) {
      float se = 0.f, ss = 0.f;
#pragma unroll
      for (int j = 0; j < 4; ++j) {
        const float v = acc[i][j][r];
        ss += v;
        se += __expf(v);
      }
#pragma unroll
      for (int off = 1; off < 16; off <<= 1) {
        se += __shfl_xor(se, off, 64);
        ss += __shfl_xor(ss, off, 64);
      }
      if (r16 == 0) {
        const int rloc = wr * 64 + i * 16 + quad * 4 + r;
        atomicAdd(&rowExp[row0 + rloc], se);
        atomicAdd(&rowSum[row0 + rloc], ss);
      }
    }
}

// loss = (1/N) sum lse - (1-s)/N * sum tgt - s/(N*V) * sum(all logits)
__global__ void finalize_kernel(const float* __restrict__ rowExp, const float* __restrict__ rowSum,
                                const float* __restrict__ tgtRow, float* __restrict__ out) {
  __shared__ float s1[256], s2[256], s3[256];
  const int t = threadIdx.x;
  float a = 0.f, b = 0.f, c = 0.f;
  for (int n = t; n < N_TOK; n += 256) {
    a += logf(rowExp[n]);
    b += rowSum[n];
    c += tgtRow[n];
  }
  s1[t] = a; s2[t] = b; s3[t] = c;
  __syncthreads();
  for (int o = 128; o > 0; o >>= 1) {
    if (t < o) { s1[t] += s1[t + o]; s2[t] += s2[t + o]; s3[t] += s3[t + o]; }
    __syncthreads();
  }
  if (t == 0) {
    const float inviN = 1.0f / (float)N_TOK;
    out[0] = s1[0] * inviN
           - (1.0f - SMOOTH) * s3[0] * inviN
           - SMOOTH * s2[0] / ((float)N_TOK * (float)VOCAB);
  }
}

extern "C" void kernel_launch(void* const* d_in, const int* in_sizes, int n_in,
                              void* d_out, int out_size, void* d_ws, size_t ws_size,
                              hipStream_t stream) {
  const float* x = (const float*)d_in[0];
  const float* W = (const float*)d_in[1];
  const int*   y = (const int*)d_in[2];
  float* out = (float*)d_out;

  char* ws = (char*)d_ws;
  float* rowExp = (float*)(ws);              // 4096 f32
  float* rowSum = (float*)(ws + 16384);      // 4096 f32
  float* tgtRow = (float*)(ws + 32768);      // 4096 f32 (fully written, no memset)
  unsigned char* Xf8 = (unsigned char*)(ws + 65536);                        // 4.19 MB
  unsigned char* Wf8 = (unsigned char*)(ws + 65536 + (size_t)N_TOK * DIM);  // 32.77 MB

  hipMemsetAsync(ws, 0, 32768, stream);  // zero rowExp/rowSum (ws poisoned 0xAA)

  tgt_dot<<<N_TOK / 4, 256, 0, stream>>>(x, W, y, tgtRow);

  const int n4x = N_TOK * DIM / 4, n4w = VOCAB * DIM / 4;
  cvt_fp8_2<<<(n4x + n4w + 255) / 256, 256, 0, stream>>>(x, (unsigned int*)Xf8, n4x,
                                                         W, (unsigned int*)Wf8, n4w);

  dim3 grid(N_TOK / BM, VOCAB / BN);  // (32, 250)
  gemm_ce<<<grid, 256, 0, stream>>>(Xf8, Wf8, rowExp, rowSum);

  finalize_kernel<<<1, 256, 0, stream>>>(rowExp, rowSum, tgtRow, out);
}